// Round 5
// baseline (679.656 us; speedup 1.0000x reference)
//
#include <hip/hip_runtime.h>
#include <hip/hip_bf16.h>

// Scatter-mean pooling: x (N=1048576, D=128) fp32, batch sorted int32 (N,),
// out (num_graphs=4096, D=128) fp32.
//
// R4 changes vs R3:
//  - Dropped nontemporal hint on LOADS (kept on the out store). The 6.3 TB/s
//    ceiling was measured with plain loads; nt early-eviction buys nothing
//    for a touch-once 512 MiB stream and may cost burst efficiency.
//  - Wave-contiguous row mapping: per pipeline iteration, wave w owns rows
//    [base + w*16, base + w*16 + 16) -- its 8 in-flight dwordx4 loads form
//    one sequential 8 KiB burst (vs 4 KiB-strided before), and offsets
//    1024*j fold into the 13-bit immediate for j<4.
// Structure unchanged: find_starts prepass (boundary detection, no binary
// search), one block per segment, LDS-reduce 8 partials, single 512 B store.

#define D       128
#define D4      32      // float4 per row
#define THREADS 256

typedef float v4f __attribute__((ext_vector_type(4)));

__global__ __launch_bounds__(256)
void find_starts_kernel(const int* __restrict__ batch,
                        int* __restrict__ starts,
                        int n_rows, int num_graphs) {
    int i = blockIdx.x * blockDim.x + threadIdx.x;
    if (i >= n_rows) return;
    int b    = batch[i];
    int prev = (i == 0) ? -1 : batch[i - 1];
    for (int s = prev + 1; s <= b; ++s) starts[s] = i;       // run starts
    if (i == n_rows - 1) {
        for (int s = b + 1; s <= num_graphs; ++s) starts[s] = n_rows; // tail
    }
}

__global__ __launch_bounds__(THREADS)
void pool_mean_kernel(const v4f* __restrict__ x,
                      const int* __restrict__ starts,
                      float* __restrict__ out) {
    const int s = blockIdx.x;

    // Two broadcast loads of the L2-hot 16 KiB starts array -- no chain.
    const int lo  = starts[s];
    const int hi  = starts[s + 1];
    const int cnt = hi - lo;
    const float inv = 1.0f / (float)(cnt > 1 ? cnt : 1);

    const int wave     = threadIdx.x >> 6;        // 0..3
    const int lane     = threadIdx.x & 63;
    const int halfwave = lane >> 5;               // 0 or 1
    const int col      = lane & 31;               // float4 column 0..31

    v4f acc = (v4f){0.f, 0.f, 0.f, 0.f};

    // Main loop: 64 rows per block iteration; wave w streams its contiguous
    // 16-row (8 KiB) burst with 8 independent loads in flight.
    int base = lo;
    {
        const v4f* p = x + (size_t)(lo + wave * 16 + halfwave) * D4 + col;
        for (; base + 64 <= hi; base += 64) {
            v4f v0 = p[0 * 2 * D4];
            v4f v1 = p[1 * 2 * D4];
            v4f v2 = p[2 * 2 * D4];
            v4f v3 = p[3 * 2 * D4];
            v4f v4 = p[4 * 2 * D4];
            v4f v5 = p[5 * 2 * D4];
            v4f v6 = p[6 * 2 * D4];
            v4f v7 = p[7 * 2 * D4];
            acc += v0; acc += v1; acc += v2; acc += v3;
            acc += v4; acc += v5; acc += v6; acc += v7;
            p += 64 * D4;
        }
    }
    // Tail (< 64 rows): stride-8 per thread, any thread->row partition is
    // fine since partials are reduced across all 8 row-lanes below.
    for (int i = base + (threadIdx.x >> 5); i < hi; i += 8) {
        acc += x[(size_t)i * D4 + col];
    }

    // Reduce 8 row-lane partials -> 1 via LDS.
    __shared__ v4f partials[8][D4];
    partials[threadIdx.x >> 5][col] = acc;
    __syncthreads();

    if (threadIdx.x < D4) {
        v4f t = partials[0][col];
        #pragma unroll
        for (int r = 1; r < 8; ++r) t += partials[r][col];
        t *= inv;
        v4f* o = (v4f*)out + (size_t)s * D4 + col;
        __builtin_nontemporal_store(t, o);
    }
}

extern "C" void kernel_launch(void* const* d_in, const int* in_sizes, int n_in,
                              void* d_out, int out_size, void* d_ws, size_t ws_size,
                              hipStream_t stream) {
    const v4f* x      = (const v4f*)d_in[0];
    const int* batch  = (const int*)d_in[1];
    float* out        = (float*)d_out;
    int* starts       = (int*)d_ws;           // (num_graphs+1) ints

    const int n_rows     = in_sizes[0] / D;   // 1048576
    const int num_graphs = out_size / D;      // 4096

    find_starts_kernel<<<(n_rows + 255) / 256, 256, 0, stream>>>(
        batch, starts, n_rows, num_graphs);
    pool_mean_kernel<<<num_graphs, THREADS, 0, stream>>>(x, starts, out);
}